// Round 2
// baseline (370.913 us; speedup 1.0000x reference)
//
#include <hip/hip_runtime.h>

#define D 64
#define KCODES 512
// N = 131072 rows; one thread per row; block = 256 rows.

__global__ __launch_bounds__(256, 1) void vq_kernel(const float* __restrict__ x,
                                                    const float* __restrict__ cb,
                                                    float* __restrict__ out) {
    __shared__ float s_cc[KCODES];
    __shared__ int   s_bi[256];

    const int t = threadIdx.x;

    // Phase 0: codebook norms into LDS (same fma order as the verified round-1
    // cc kernel: single accumulator, d ascending). ~128 fma/thread — noise.
    #pragma unroll
    for (int i = 0; i < 2; ++i) {
        const int k = t + 256 * i;
        const float4* cv = (const float4*)(cb + k * D);
        float s = 0.f;
        #pragma unroll
        for (int q = 0; q < 16; ++q) {
            float4 c = cv[q];
            s = fmaf(c.x, c.x, s);
            s = fmaf(c.y, c.y, s);
            s = fmaf(c.z, c.z, s);
            s = fmaf(c.w, c.w, s);
        }
        s_cc[k] = s;
    }
    __syncthreads();

    // Row into registers. launch_bounds(256,1) => allocator may use fat waves;
    // explicit float4 vars + constant indices keep SROA happy (round 1: the
    // plain float[64] array was spilled at VGPR=36 -> 151MB scratch traffic).
    const size_t row = (size_t)blockIdx.x * 256 + t;
    const float4* xv = (const float4*)(x + row * D);
    float4 xr[16];
    #pragma unroll
    for (int i = 0; i < 16; ++i) xr[i] = xv[i];

    float xx = 0.f;   // sequential d=0..63, same order as round 1
    #pragma unroll
    for (int i = 0; i < 16; ++i) {
        xx = fmaf(xr[i].x, xr[i].x, xx);
        xx = fmaf(xr[i].y, xr[i].y, xx);
        xx = fmaf(xr[i].z, xr[i].z, xx);
        xx = fmaf(xr[i].w, xr[i].w, xx);
    }

    float best = __builtin_inff();
    int bi = 0;
    // cb address is wave-uniform -> scalar loads (s_load) feed the FMAs as the
    // single allowed SGPR operand; unroll 2 gives the scheduler two codes of
    // s_load latency overlap (only 2 waves/SIMD resident on this grid).
    #pragma unroll 2
    for (int k = 0; k < KCODES; ++k) {
        const float4* cv = (const float4*)(cb + k * D);
        float dot0 = 0.f, dot1 = 0.f;   // even/odd accumulators, round-1 order
        #pragma unroll
        for (int i = 0; i < 16; ++i) {
            float4 c = cv[i];
            dot0 = fmaf(xr[i].x, c.x, dot0);
            dot1 = fmaf(xr[i].y, c.y, dot1);
            dot0 = fmaf(xr[i].z, c.z, dot0);
            dot1 = fmaf(xr[i].w, c.w, dot1);
        }
        const float dist = (xx - 2.f * (dot0 + dot1)) + s_cc[k];
        if (dist < best) { best = dist; bi = k; }   // strict < = first-occurrence
    }

    s_bi[t] = bi;
    __syncthreads();

    // Coalesced gather+store: block tile = 256 rows x 64 floats = 4096 float4.
    // Per wave at fixed j: stores are contiguous 1KB; cb reads span 4 rows, L1-hot.
    float4* outv = (float4*)(out + (size_t)blockIdx.x * (256 * D));
    const float4* cbv = (const float4*)cb;
    #pragma unroll
    for (int j = 0; j < 16; ++j) {
        const int flat4 = j * 256 + t;   // 0..4095
        const int r = flat4 >> 4;        // row within block
        const int q = flat4 & 15;        // float4 within row
        outv[flat4] = cbv[s_bi[r] * 16 + q];
    }
}

extern "C" void kernel_launch(void* const* d_in, const int* in_sizes, int n_in,
                              void* d_out, int out_size, void* d_ws, size_t ws_size,
                              hipStream_t stream) {
    const float* x  = (const float*)d_in[0];   // 131072 x 64
    const float* cb = (const float*)d_in[1];   // 512 x 64
    float* out = (float*)d_out;

    const int N = in_sizes[0] / D;             // 131072
    vq_kernel<<<N / 256, 256, 0, stream>>>(x, cb, out);
}